// Round 1
// baseline (1211.481 us; speedup 1.0000x reference)
//
#include <hip/hip_runtime.h>
#include <cstdint>
#include <cstddef>

// ---------- problem constants ----------
#define DIM      1024
#define GROUP    16
#define LORA     20
#define NLAYERS  18
#define NBLOCKS  6
#define BATCH    8192
#define EPS      1e-5f

typedef __bf16 bf16_8 __attribute__((ext_vector_type(8)));
typedef __bf16 bf16_4 __attribute__((ext_vector_type(4)));
typedef float  f32x4  __attribute__((ext_vector_type(4)));

// ---------------------------------------------------------------------------
// Weight prep: W_total[l][o][k] = qw*scale + sum_r B[o][r]*A[r][k]
// split into bf16 hi/lo.  One block per (l,o) row, 256 threads x 4 k each.
// ---------------------------------------------------------------------------
__global__ __launch_bounds__(256) void wprep_kernel(
    const int* __restrict__ qw, const float* __restrict__ sc,
    const float* __restrict__ la, const float* __restrict__ lb,
    __bf16* __restrict__ whi, __bf16* __restrict__ wlo) {
  const int l = blockIdx.x >> 10;
  const int o = blockIdx.x & 1023;
  const int tid = threadIdx.x;
  __shared__ float Br[LORA];
  if (tid < LORA) Br[tid] = lb[((size_t)l * DIM + o) * LORA + tid];
  __syncthreads();

  const size_t rowbase = ((size_t)l * DIM + o) * DIM;  // element base of W row
  const int4 q4 = *(const int4*)&qw[rowbase + tid * 4];
  const float s = sc[((size_t)l * DIM + o) * (DIM / GROUP) + (tid >> 2)];
  float a0 = (float)q4.x * s, a1 = (float)q4.y * s,
        a2 = (float)q4.z * s, a3 = (float)q4.w * s;

  const float* A = la + (size_t)l * LORA * DIM + tid * 4;
#pragma unroll
  for (int r = 0; r < LORA; ++r) {
    const float4 av = *(const float4*)(A + (size_t)r * DIM);
    const float br = Br[r];
    a0 += br * av.x; a1 += br * av.y; a2 += br * av.z; a3 += br * av.w;
  }
  const __bf16 h0 = (__bf16)a0, h1 = (__bf16)a1, h2 = (__bf16)a2, h3 = (__bf16)a3;
  const bf16_4 hv = {h0, h1, h2, h3};
  const bf16_4 lv = {(__bf16)(a0 - (float)h0), (__bf16)(a1 - (float)h1),
                     (__bf16)(a2 - (float)h2), (__bf16)(a3 - (float)h3)};
  *(bf16_4*)&whi[rowbase + tid * 4] = hv;
  *(bf16_4*)&wlo[rowbase + tid * 4] = lv;
}

// ---------------------------------------------------------------------------
// x prep: f32 -> bf16 hi/lo split (one float4 per thread)
// ---------------------------------------------------------------------------
__global__ __launch_bounds__(256) void xprep_kernel(
    const float* __restrict__ x, __bf16* __restrict__ hi, __bf16* __restrict__ lo) {
  const size_t i = (size_t)blockIdx.x * 256 + threadIdx.x;
  const float4 v = ((const float4*)x)[i];
  const __bf16 h0 = (__bf16)v.x, h1 = (__bf16)v.y, h2 = (__bf16)v.z, h3 = (__bf16)v.w;
  const bf16_4 hv = {h0, h1, h2, h3};
  const bf16_4 lv = {(__bf16)(v.x - (float)h0), (__bf16)(v.y - (float)h1),
                     (__bf16)(v.z - (float)h2), (__bf16)(v.w - (float)h3)};
  ((bf16_4*)hi)[i] = hv;
  ((bf16_4*)lo)[i] = lv;
}

// ---------------------------------------------------------------------------
// 3-pass split-bf16 GEMM: out[n,o] = sum_k x[n,k]*W[o,k]  (+bias, +epilogue)
// 128x128 tile, BK=64, 4 waves (2x2), mfma_f32_16x16x32_bf16.
// ---------------------------------------------------------------------------
__device__ __forceinline__ void stage_tile(const __bf16* __restrict__ g, int row0,
                                           int k0, __bf16* lds, int wv, int lane) {
  const int sub = lane >> 3;          // row within 1KB chunk (8 rows of 128B)
  const int kcol = (lane & 7) * 8;    // 8 bf16 = 16B per lane
#pragma unroll
  for (int c = 0; c < 4; ++c) {
    const int chunk = wv * 4 + c;
    const __bf16* gp = g + (size_t)(row0 + chunk * 8 + sub) * DIM + k0 + kcol;
    __builtin_amdgcn_global_load_lds(
        (const __attribute__((address_space(1))) void*)gp,
        (__attribute__((address_space(3))) void*)(lds + chunk * 512), 16, 0, 0);
  }
}

template <bool RELU_SPLIT>
__global__ __launch_bounds__(256, 2) void gemm3_kernel(
    const __bf16* __restrict__ Ah, const __bf16* __restrict__ Al,
    const __bf16* __restrict__ Bh, const __bf16* __restrict__ Bl,
    const float* __restrict__ bias,
    __bf16* __restrict__ Oh, __bf16* __restrict__ Ol,      // RELU_SPLIT path
    const float* __restrict__ Hin, float* __restrict__ Sout) {  // residual path
  __shared__ __bf16 sA[2][128 * 64];
  __shared__ __bf16 sB[2][128 * 64];

  const int tid = threadIdx.x;
  const int lane = tid & 63;
  const int wv = tid >> 6;
  const int wm = wv >> 1, wn = wv & 1;
  const int tm = blockIdx.x >> 3, tn = blockIdx.x & 7;
  const int rowA = tm * 128, rowB = tn * 128;

  f32x4 acc[4][4];
#pragma unroll
  for (int m = 0; m < 4; ++m)
#pragma unroll
    for (int n = 0; n < 4; ++n) acc[m][n] = f32x4{0.f, 0.f, 0.f, 0.f};

  const int lr = lane & 15;
  const int lk = (lane >> 4) * 8;

  for (int kt = 0; kt < DIM / 64; ++kt) {
    const int k0 = kt * 64;
    stage_tile(Ah, rowA, k0, &sA[0][0], wv, lane);
    stage_tile(Al, rowA, k0, &sA[1][0], wv, lane);
    stage_tile(Bh, rowB, k0, &sB[0][0], wv, lane);
    stage_tile(Bl, rowB, k0, &sB[1][0], wv, lane);
    __syncthreads();

#pragma unroll
    for (int kk = 0; kk < 2; ++kk) {
      const int ko = kk * 32 + lk;
      bf16_8 ah[4], al[4], bh[4], bl[4];
#pragma unroll
      for (int m = 0; m < 4; ++m) {
        const int idx = (wm * 64 + m * 16 + lr) * 64 + ko;
        ah[m] = *(const bf16_8*)&sA[0][idx];
        al[m] = *(const bf16_8*)&sA[1][idx];
      }
#pragma unroll
      for (int n = 0; n < 4; ++n) {
        const int idx = (wn * 64 + n * 16 + lr) * 64 + ko;
        bh[n] = *(const bf16_8*)&sB[0][idx];
        bl[n] = *(const bf16_8*)&sB[1][idx];
      }
#pragma unroll
      for (int m = 0; m < 4; ++m)
#pragma unroll
        for (int n = 0; n < 4; ++n) {
          acc[m][n] = __builtin_amdgcn_mfma_f32_16x16x32_bf16(ah[m], bh[n], acc[m][n], 0, 0, 0);
          acc[m][n] = __builtin_amdgcn_mfma_f32_16x16x32_bf16(al[m], bh[n], acc[m][n], 0, 0, 0);
          acc[m][n] = __builtin_amdgcn_mfma_f32_16x16x32_bf16(ah[m], bl[n], acc[m][n], 0, 0, 0);
        }
    }
    __syncthreads();
  }

  // epilogue: C/D layout col=lane&15, row=(lane>>4)*4+reg  [m89-verified]
  const int lr4 = (lane >> 4) * 4;
#pragma unroll
  for (int n = 0; n < 4; ++n) {
    const int col = tn * 128 + wn * 64 + n * 16 + lr;
    const float bv = bias[col];
#pragma unroll
    for (int m = 0; m < 4; ++m) {
      const int row0 = tm * 128 + wm * 64 + m * 16 + lr4;
#pragma unroll
      for (int r = 0; r < 4; ++r) {
        float v = acc[m][n][r] + bv;
        const size_t idx = (size_t)(row0 + r) * DIM + col;
        if constexpr (RELU_SPLIT) {
          v = fmaxf(v, 0.f);
          const __bf16 h = (__bf16)v;
          Oh[idx] = h;
          Ol[idx] = (__bf16)(v - (float)h);
        } else {
          Sout[idx] = v + Hin[idx];
        }
      }
    }
  }
}

// ---------------------------------------------------------------------------
// Row LayerNorm: H = LN(S)*w+b (f32) plus bf16 hi/lo split of H.
// One 256-thread block per row (4 f32 per thread).
// ---------------------------------------------------------------------------
__global__ __launch_bounds__(256) void ln_kernel(
    const float* __restrict__ S, const float* __restrict__ w,
    const float* __restrict__ b, float* __restrict__ H,
    __bf16* __restrict__ phi, __bf16* __restrict__ plo) {
  const int row = blockIdx.x;
  const int tid = threadIdx.x;
  const int lane = tid & 63;
  const int wv = tid >> 6;
  const float4 v = ((const float4*)(S + (size_t)row * DIM))[tid];

  float s = v.x + v.y + v.z + v.w;
#pragma unroll
  for (int m = 32; m; m >>= 1) s += __shfl_xor(s, m, 64);
  __shared__ float red[8];
  if (lane == 0) red[wv] = s;
  __syncthreads();
  const float mean = (red[0] + red[1] + red[2] + red[3]) * (1.f / DIM);

  const float d0 = v.x - mean, d1 = v.y - mean, d2 = v.z - mean, d3 = v.w - mean;
  float q = d0 * d0 + d1 * d1 + d2 * d2 + d3 * d3;
#pragma unroll
  for (int m = 32; m; m >>= 1) q += __shfl_xor(q, m, 64);
  if (lane == 0) red[4 + wv] = q;
  __syncthreads();
  const float var = (red[4] + red[5] + red[6] + red[7]) * (1.f / DIM);
  const float inv = 1.f / sqrtf(var + EPS);

  const float4 wv4 = ((const float4*)w)[tid];
  const float4 bv4 = ((const float4*)b)[tid];
  const float y0 = d0 * inv * wv4.x + bv4.x;
  const float y1 = d1 * inv * wv4.y + bv4.y;
  const float y2 = d2 * inv * wv4.z + bv4.z;
  const float y3 = d3 * inv * wv4.w + bv4.w;

  ((float4*)(H + (size_t)row * DIM))[tid] = float4{y0, y1, y2, y3};
  const __bf16 h0 = (__bf16)y0, h1 = (__bf16)y1, h2 = (__bf16)y2, h3 = (__bf16)y3;
  const bf16_4 hv = {h0, h1, h2, h3};
  const bf16_4 lv = {(__bf16)(y0 - (float)h0), (__bf16)(y1 - (float)h1),
                     (__bf16)(y2 - (float)h2), (__bf16)(y3 - (float)h3)};
  const size_t base4 = (size_t)row * (DIM / 4) + tid;
  ((bf16_4*)phi)[base4] = hv;
  ((bf16_4*)plo)[base4] = lv;
}

// ---------------------------------------------------------------------------
// launch
// ---------------------------------------------------------------------------
extern "C" void kernel_launch(void* const* d_in, const int* in_sizes, int n_in,
                              void* d_out, int out_size, void* d_ws, size_t ws_size,
                              hipStream_t stream) {
  const float* x   = (const float*)d_in[0];
  const int*   qw  = (const int*)d_in[1];
  const float* sc  = (const float*)d_in[2];
  const float* bias= (const float*)d_in[3];
  const float* la  = (const float*)d_in[4];
  const float* lb  = (const float*)d_in[5];
  const float* lnw = (const float*)d_in[6];
  const float* lnb = (const float*)d_in[7];
  float* out = (float*)d_out;
  char* ws = (char*)d_ws;

  // workspace layout (bytes)
  const size_t W_ELEMS = (size_t)NLAYERS * DIM * DIM;       // 18874368
  __bf16* WHI = (__bf16*)(ws);                               // 37748736 B
  __bf16* WLO = (__bf16*)(ws + 37748736);                    // 37748736 B
  __bf16* P0H = (__bf16*)(ws + 75497472);                    // 16777216 B
  __bf16* P0L = (__bf16*)(ws + 92274688);                    // 16777216 B
  __bf16* P1H = (__bf16*)(ws + 109051904);                   // 16777216 B
  __bf16* P1L = (__bf16*)(ws + 125829120);                   // 16777216 B
  float*  Sb  = (float*)(ws + 109051904);                    // aliases P1 (33554432 B)
  float*  Hb  = (float*)(ws + 142606336);                    // 33554432 B -> total 176160768
  (void)W_ELEMS; (void)ws_size; (void)in_sizes; (void)n_in; (void)out_size;

  xprep_kernel<<<BATCH * DIM / (256 * 4), 256, 0, stream>>>(x, P0H, P0L);
  wprep_kernel<<<NLAYERS * DIM, 256, 0, stream>>>(qw, sc, la, lb, WHI, WLO);

  const dim3 ggrid(BATCH / 128 * (DIM / 128));  // 64 * 8 = 512
  for (int blk = 0; blk < NBLOCKS; ++blk) {
    const int li = blk * 3;
    const size_t w0 = (size_t)li * DIM * DIM;
    const size_t w1 = (size_t)(li + 1) * DIM * DIM;
    const size_t w2 = (size_t)(li + 2) * DIM * DIM;

    // j0: P0 -> P1 (relu + split)
    gemm3_kernel<true><<<ggrid, 256, 0, stream>>>(
        P0H, P0L, WHI + w0, WLO + w0, bias + (size_t)li * DIM,
        P1H, P1L, nullptr, nullptr);
    // j1: P1 -> P0 (relu + split)
    gemm3_kernel<true><<<ggrid, 256, 0, stream>>>(
        P1H, P1L, WHI + w1, WLO + w1, bias + (size_t)(li + 1) * DIM,
        P0H, P0L, nullptr, nullptr);
    // j2: P0 -> S = h + y   (residual add, f32)
    const float* hin = (blk == 0) ? x : Hb;
    float* sout = (blk == NBLOCKS - 1) ? out : Sb;
    gemm3_kernel<false><<<ggrid, 256, 0, stream>>>(
        P0H, P0L, WHI + w2, WLO + w2, bias + (size_t)(li + 2) * DIM,
        nullptr, nullptr, hin, sout);
    // LayerNorm between blocks: S -> H (f32) + P0 hi/lo (next block input)
    if (blk < NBLOCKS - 1) {
      ln_kernel<<<BATCH, 256, 0, stream>>>(Sb, lnw + (size_t)blk * DIM,
                                           lnb + (size_t)blk * DIM, Hb, P0H, P0L);
    }
  }
}

// Round 2
// 1088.192 us; speedup vs baseline: 1.1133x; 1.1133x over previous
//
#include <hip/hip_runtime.h>
#include <cstdint>
#include <cstddef>

// ---------- problem constants ----------
#define DIM      1024
#define GROUP    16
#define LORA     20
#define NLAYERS  18
#define NBLOCKS  6
#define BATCH    8192
#define EPS      1e-5f

typedef __bf16 bf16_8 __attribute__((ext_vector_type(8)));
typedef __bf16 bf16_4 __attribute__((ext_vector_type(4)));
typedef float  f32x4  __attribute__((ext_vector_type(4)));

// ---------------------------------------------------------------------------
// Weight prep: W_total[l][o][k] = qw*scale + sum_r B[o][r]*A[r][k], split bf16
// hi/lo. Block = (layer, 64-row group, 512-col half); A-slice staged in LDS so
// global A traffic is 576*40KB = 23MB instead of 1.5GB of L2 re-reads.
// ---------------------------------------------------------------------------
__global__ __launch_bounds__(256) void wprep_kernel(
    const int* __restrict__ qw, const float* __restrict__ sc,
    const float* __restrict__ la, const float* __restrict__ lb,
    __bf16* __restrict__ whi, __bf16* __restrict__ wlo) {
  const int l  = blockIdx.x >> 5;          // 18 layers
  const int og = (blockIdx.x >> 1) & 15;   // 16 row-groups of 64
  const int cg = blockIdx.x & 1;           // 2 col-halves of 512
  const int tid = threadIdx.x;

  __shared__ float As[LORA * 512];   // 40 KB  A[l][j][cg*512 + c]
  __shared__ float Bs[64 * LORA];    // 5 KB   B rows og*64..+63

  const float* Abase = la + (size_t)l * LORA * DIM + cg * 512;
#pragma unroll
  for (int i = 0; i < 10; ++i) {           // 20*512 floats / (256 thr * 4)
    const int f4 = i * 256 + tid;
    const int j  = f4 >> 7;
    const int c4 = f4 & 127;
    ((float4*)As)[f4] = *(const float4*)(Abase + (size_t)j * DIM + c4 * 4);
  }
  const float* Bbase = lb + ((size_t)l * DIM + og * 64) * LORA;  // contiguous 1280
#pragma unroll
  for (int i = 0; i < 5; ++i) Bs[i * 256 + tid] = Bbase[i * 256 + tid];
  __syncthreads();

  const int colg = (tid & 127) * 4;        // col within the 512 slice
  const int rh   = tid >> 7;               // row half (0/1)
#pragma unroll 1
  for (int s = 0; s < 32; ++s) {
    const int r    = rh * 32 + s;
    const int orow = og * 64 + r;
    const size_t wbase = ((size_t)l * DIM + orow) * DIM + cg * 512 + colg;
    const int4 q4 = *(const int4*)&qw[wbase];
    const float sv = sc[((size_t)l * DIM + orow) * (DIM / GROUP) + ((cg * 512 + colg) >> 4)];
    float a0 = q4.x * sv, a1 = q4.y * sv, a2 = q4.z * sv, a3 = q4.w * sv;
    const float* Br = &Bs[r * LORA];
#pragma unroll
    for (int j = 0; j < LORA; ++j) {
      const float bj = Br[j];
      const float* Aj = &As[j * 512 + colg];
      a0 += bj * Aj[0]; a1 += bj * Aj[1]; a2 += bj * Aj[2]; a3 += bj * Aj[3];
    }
    const __bf16 h0 = (__bf16)a0, h1 = (__bf16)a1, h2 = (__bf16)a2, h3 = (__bf16)a3;
    const bf16_4 hv = {h0, h1, h2, h3};
    const bf16_4 lv = {(__bf16)(a0 - (float)h0), (__bf16)(a1 - (float)h1),
                       (__bf16)(a2 - (float)h2), (__bf16)(a3 - (float)h3)};
    *(bf16_4*)&whi[wbase] = hv;
    *(bf16_4*)&wlo[wbase] = lv;
  }
}

// ---------------------------------------------------------------------------
// x prep: f32 -> bf16 hi/lo split
// ---------------------------------------------------------------------------
__global__ __launch_bounds__(256) void xprep_kernel(
    const float* __restrict__ x, __bf16* __restrict__ hi, __bf16* __restrict__ lo) {
  const size_t i = (size_t)blockIdx.x * 256 + threadIdx.x;
  const float4 v = ((const float4*)x)[i];
  const __bf16 h0 = (__bf16)v.x, h1 = (__bf16)v.y, h2 = (__bf16)v.z, h3 = (__bf16)v.w;
  const bf16_4 hv = {h0, h1, h2, h3};
  const bf16_4 lv = {(__bf16)(v.x - (float)h0), (__bf16)(v.y - (float)h1),
                     (__bf16)(v.z - (float)h2), (__bf16)(v.w - (float)h3)};
  ((bf16_4*)hi)[i] = hv;
  ((bf16_4*)lo)[i] = lv;
}

// ---------------------------------------------------------------------------
// 3-pass split-bf16 GEMM, T3/T4 pipelined.
// BM=256, BN=128, BK=32, 512 thr (8 waves: 4M x 2N), per-wave 64x64 out.
// 3 LDS buffers (48KB each = Ah|Al|Bh|Bl), counted vmcnt(6): 2 tiles in flight.
// BK=32 rows are 64B -> frag ds_read_b128 is bank-uniform (no swizzle needed).
// ---------------------------------------------------------------------------
#define BUF_ELEMS 24576   // 48 KB in bf16 elems
#define OFF_AL    8192
#define OFF_BH    16384
#define OFF_BL    20480

template <int NISSUE>
__device__ __forceinline__ void stage32(const __bf16* __restrict__ g, int row0, int k0,
                                        __bf16* lds, int tid) {
  const int wvbase = (tid >> 6) * 512;     // elems: wave-uniform LDS base
#pragma unroll
  for (int i = 0; i < NISSUE; ++i) {
    const int Lb = i * 8192 + tid * 16;    // linear byte in tile
    const int r  = Lb >> 6;                // 64 B per row
    const int ce = (Lb & 63) >> 1;         // elem col within row
    const __bf16* gp = g + (size_t)(row0 + r) * DIM + k0 + ce;
    __builtin_amdgcn_global_load_lds(
        (const __attribute__((address_space(1))) void*)gp,
        (__attribute__((address_space(3))) void*)(lds + i * 4096 + wvbase), 16, 0, 0);
  }
}

__device__ __forceinline__ void stage_all(const __bf16* __restrict__ Ah,
                                          const __bf16* __restrict__ Al,
                                          const __bf16* __restrict__ Bh,
                                          const __bf16* __restrict__ Bl,
                                          int rowA, int rowB, int k0,
                                          __bf16* sbuf, int tid) {
  stage32<2>(Ah, rowA, k0, sbuf, tid);
  stage32<2>(Al, rowA, k0, sbuf + OFF_AL, tid);
  stage32<1>(Bh, rowB, k0, sbuf + OFF_BH, tid);
  stage32<1>(Bl, rowB, k0, sbuf + OFF_BL, tid);
}

template <bool RELU_SPLIT>
__global__ __launch_bounds__(512, 2) void gemm3_kernel(
    const __bf16* __restrict__ Ah, const __bf16* __restrict__ Al,
    const __bf16* __restrict__ Bh, const __bf16* __restrict__ Bl,
    const float* __restrict__ bias,
    __bf16* __restrict__ Oh, __bf16* __restrict__ Ol,
    const float* __restrict__ Hin, float* __restrict__ Sout) {
  extern __shared__ __bf16 smem[];         // 3 * 24576 elems = 144 KB

  const int tid  = threadIdx.x;
  const int lane = tid & 63;
  const int wv   = tid >> 6;
  const int wm   = wv >> 1, wn = wv & 1;
  // XCD-chunked swizzle: 256 wg, 8 XCDs -> each XCD: 4 A-panels x all 8 B-panels
  const int s  = ((blockIdx.x & 7) << 5) + (blockIdx.x >> 3);
  const int tm = s >> 3, tn = s & 7;
  const int rowA = tm * 256, rowB = tn * 128;

  const int lr = lane & 15;
  const int c0 = (lane >> 4) * 8;

  int offA[4], offB[4];
#pragma unroll
  for (int m = 0; m < 4; ++m) offA[m] = (wm * 64 + m * 16 + lr) * 32 + c0;
#pragma unroll
  for (int n = 0; n < 4; ++n) offB[n] = OFF_BH + (wn * 64 + n * 16 + lr) * 32 + c0;

  f32x4 acc[4][4];
#pragma unroll
  for (int m = 0; m < 4; ++m)
#pragma unroll
    for (int n = 0; n < 4; ++n) acc[m][n] = f32x4{0.f, 0.f, 0.f, 0.f};

  auto compute_tile = [&](const __bf16* buf) {
    bf16_8 a_h[4], a_l[4], b_h[4], b_l[4];
#pragma unroll
    for (int m = 0; m < 4; ++m) {
      a_h[m] = *(const bf16_8*)&buf[offA[m]];
      a_l[m] = *(const bf16_8*)&buf[offA[m] + OFF_AL];
    }
#pragma unroll
    for (int n = 0; n < 4; ++n) {
      b_h[n] = *(const bf16_8*)&buf[offB[n]];
      b_l[n] = *(const bf16_8*)&buf[offB[n] + (OFF_BL - OFF_BH)];
    }
    __builtin_amdgcn_s_setprio(1);
#pragma unroll
    for (int m = 0; m < 4; ++m)
#pragma unroll
      for (int n = 0; n < 4; ++n) {
        acc[m][n] = __builtin_amdgcn_mfma_f32_16x16x32_bf16(a_h[m], b_h[n], acc[m][n], 0, 0, 0);
        acc[m][n] = __builtin_amdgcn_mfma_f32_16x16x32_bf16(a_l[m], b_h[n], acc[m][n], 0, 0, 0);
        acc[m][n] = __builtin_amdgcn_mfma_f32_16x16x32_bf16(a_h[m], b_l[n], acc[m][n], 0, 0, 0);
      }
    __builtin_amdgcn_s_setprio(0);
  };

  // prologue: tiles 0 and 1 in flight; wait for tile 0 only (vmcnt 6 = tile 1)
  stage_all(Ah, Al, Bh, Bl, rowA, rowB, 0, smem, tid);
  stage_all(Ah, Al, Bh, Bl, rowA, rowB, 32, smem + BUF_ELEMS, tid);
  asm volatile("s_waitcnt vmcnt(6)" ::: "memory");
  __builtin_amdgcn_s_barrier();

  int cur = 0;
#pragma unroll 1
  for (int kt = 0; kt < 30; ++kt) {
    int pb = cur + 2; if (pb >= 3) pb -= 3;
    stage_all(Ah, Al, Bh, Bl, rowA, rowB, (kt + 2) * 32, smem + pb * BUF_ELEMS, tid);
    compute_tile(smem + cur * BUF_ELEMS);
    // tile kt+1's 6 loads are the oldest outstanding; newest 6 (kt+2) may fly on
    asm volatile("s_waitcnt vmcnt(6)" ::: "memory");
    __builtin_amdgcn_s_barrier();
    ++cur; if (cur == 3) cur = 0;
  }
  // kt = 30: no more staging; drain tile 31
  compute_tile(smem + cur * BUF_ELEMS);
  asm volatile("s_waitcnt vmcnt(0)" ::: "memory");
  __builtin_amdgcn_s_barrier();
  ++cur; if (cur == 3) cur = 0;
  // kt = 31
  compute_tile(smem + cur * BUF_ELEMS);

  // epilogue: C/D layout col=lane&15, row=(lane>>4)*4+reg  [m89-verified]
  const int lr4 = (lane >> 4) * 4;
#pragma unroll
  for (int n = 0; n < 4; ++n) {
    const int col = tn * 128 + wn * 64 + n * 16 + lr;
    const float bv = bias[col];
#pragma unroll
    for (int m = 0; m < 4; ++m) {
      const int row0 = tm * 256 + wm * 64 + m * 16 + lr4;
#pragma unroll
      for (int r = 0; r < 4; ++r) {
        float v = acc[m][n][r] + bv;
        const size_t idx = (size_t)(row0 + r) * DIM + col;
        if constexpr (RELU_SPLIT) {
          v = fmaxf(v, 0.f);
          const __bf16 h = (__bf16)v;
          Oh[idx] = h;
          Ol[idx] = (__bf16)(v - (float)h);
        } else {
          Sout[idx] = v + Hin[idx];
        }
      }
    }
  }
}

// ---------------------------------------------------------------------------
// Row LayerNorm: H = LN(S)*w+b (f32) plus bf16 hi/lo split of H.
// ---------------------------------------------------------------------------
__global__ __launch_bounds__(256) void ln_kernel(
    const float* __restrict__ S, const float* __restrict__ w,
    const float* __restrict__ b, float* __restrict__ H,
    __bf16* __restrict__ phi, __bf16* __restrict__ plo) {
  const int row = blockIdx.x;
  const int tid = threadIdx.x;
  const int lane = tid & 63;
  const int wv = tid >> 6;
  const float4 v = ((const float4*)(S + (size_t)row * DIM))[tid];

  float s = v.x + v.y + v.z + v.w;
#pragma unroll
  for (int m = 32; m; m >>= 1) s += __shfl_xor(s, m, 64);
  __shared__ float red[8];
  if (lane == 0) red[wv] = s;
  __syncthreads();
  const float mean = (red[0] + red[1] + red[2] + red[3]) * (1.f / DIM);

  const float d0 = v.x - mean, d1 = v.y - mean, d2 = v.z - mean, d3 = v.w - mean;
  float q = d0 * d0 + d1 * d1 + d2 * d2 + d3 * d3;
#pragma unroll
  for (int m = 32; m; m >>= 1) q += __shfl_xor(q, m, 64);
  if (lane == 0) red[4 + wv] = q;
  __syncthreads();
  const float var = (red[4] + red[5] + red[6] + red[7]) * (1.f / DIM);
  const float inv = 1.f / sqrtf(var + EPS);

  const float4 wv4 = ((const float4*)w)[tid];
  const float4 bv4 = ((const float4*)b)[tid];
  const float y0 = d0 * inv * wv4.x + bv4.x;
  const float y1 = d1 * inv * wv4.y + bv4.y;
  const float y2 = d2 * inv * wv4.z + bv4.z;
  const float y3 = d3 * inv * wv4.w + bv4.w;

  ((float4*)(H + (size_t)row * DIM))[tid] = float4{y0, y1, y2, y3};
  const __bf16 h0 = (__bf16)y0, h1 = (__bf16)y1, h2 = (__bf16)y2, h3 = (__bf16)y3;
  const bf16_4 hv = {h0, h1, h2, h3};
  const bf16_4 lv = {(__bf16)(y0 - (float)h0), (__bf16)(y1 - (float)h1),
                     (__bf16)(y2 - (float)h2), (__bf16)(y3 - (float)h3)};
  const size_t base4 = (size_t)row * (DIM / 4) + tid;
  ((bf16_4*)phi)[base4] = hv;
  ((bf16_4*)plo)[base4] = lv;
}

// ---------------------------------------------------------------------------
// launch
// ---------------------------------------------------------------------------
extern "C" void kernel_launch(void* const* d_in, const int* in_sizes, int n_in,
                              void* d_out, int out_size, void* d_ws, size_t ws_size,
                              hipStream_t stream) {
  const float* x   = (const float*)d_in[0];
  const int*   qw  = (const int*)d_in[1];
  const float* sc  = (const float*)d_in[2];
  const float* bias= (const float*)d_in[3];
  const float* la  = (const float*)d_in[4];
  const float* lb  = (const float*)d_in[5];
  const float* lnw = (const float*)d_in[6];
  const float* lnb = (const float*)d_in[7];
  float* out = (float*)d_out;
  char* ws = (char*)d_ws;

  __bf16* WHI = (__bf16*)(ws);
  __bf16* WLO = (__bf16*)(ws + 37748736);
  __bf16* P0H = (__bf16*)(ws + 75497472);
  __bf16* P0L = (__bf16*)(ws + 92274688);
  __bf16* P1H = (__bf16*)(ws + 109051904);
  __bf16* P1L = (__bf16*)(ws + 125829120);
  float*  Sb  = (float*)(ws + 109051904);   // aliases P1
  float*  Hb  = (float*)(ws + 142606336);
  (void)ws_size; (void)in_sizes; (void)n_in; (void)out_size;

  xprep_kernel<<<BATCH * DIM / (256 * 4), 256, 0, stream>>>(x, P0H, P0L);
  wprep_kernel<<<NLAYERS * 32, 256, 0, stream>>>(qw, sc, la, lb, WHI, WLO);

  const dim3 ggrid(BATCH / 256 * (DIM / 128));  // 32 * 8 = 256
  const size_t smem_bytes = 3 * BUF_ELEMS * sizeof(__bf16);  // 147456
  for (int blk = 0; blk < NBLOCKS; ++blk) {
    const int li = blk * 3;
    const size_t w0 = (size_t)li * DIM * DIM;
    const size_t w1 = (size_t)(li + 1) * DIM * DIM;
    const size_t w2 = (size_t)(li + 2) * DIM * DIM;

    gemm3_kernel<true><<<ggrid, 512, smem_bytes, stream>>>(
        P0H, P0L, WHI + w0, WLO + w0, bias + (size_t)li * DIM,
        P1H, P1L, nullptr, nullptr);
    gemm3_kernel<true><<<ggrid, 512, smem_bytes, stream>>>(
        P1H, P1L, WHI + w1, WLO + w1, bias + (size_t)(li + 1) * DIM,
        P0H, P0L, nullptr, nullptr);
    const float* hin = (blk == 0) ? x : Hb;
    float* sout = (blk == NBLOCKS - 1) ? out : Sb;
    gemm3_kernel<false><<<ggrid, 512, smem_bytes, stream>>>(
        P0H, P0L, WHI + w2, WLO + w2, bias + (size_t)(li + 2) * DIM,
        nullptr, nullptr, hin, sout);
    if (blk < NBLOCKS - 1) {
      ln_kernel<<<BATCH, 256, 0, stream>>>(Sb, lnw + (size_t)blk * DIM,
                                           lnb + (size_t)blk * DIM, Hb, P0H, P0L);
    }
  }
}